// Round 13
// baseline (159.979 us; speedup 1.0000x reference)
//
#include <hip/hip_runtime.h>
#include <math.h>

#define MM 16384
#define NN 8192
#define DD 128

#define L2E  1.4426950408889634f
#define COEF 0.15915494309189535f   // 1/(2*pi)

// ---------------------------------------------------------------------------
// fp16 helpers (RNE via v_cvt_f16_f32)
// ---------------------------------------------------------------------------
__device__ __forceinline__ unsigned short f2h(float f) {
    _Float16 h = (_Float16)f;
    unsigned short u;
    __builtin_memcpy(&u, &h, 2);
    return u;
}
__device__ __forceinline__ float h2f(unsigned short u) {
    _Float16 h;
    __builtin_memcpy(&h, &u, 2);
    return (float)h;
}

__device__ __forceinline__ void async16(short* lds, const short* g) {
    __builtin_amdgcn_global_load_lds(
        (const __attribute__((address_space(1))) unsigned int*)g,
        (__attribute__((address_space(3))) unsigned int*)lds,
        16, 0, 0);
}

typedef __attribute__((ext_vector_type(8))) _Float16 f16x8;
typedef __attribute__((ext_vector_type(4))) float f32x4;

// ---------------------------------------------------------------------------
// Pre-pass v4 (unchanged) — one 16-row block per 256-thread block.
// Layout: Cat = [rowblock rb][chunk][64 granules of 16B], granule (rp,gk) at
// slot rp*4+((gk+(rp>>1))&3) (bank swizzle -> post-DMA LDS frag reads
// conflict-free). A: 8 chunks (0-3 = fp16(x*L2E) hi, 4-7 = fp16 residual).
// B: 4 chunks (fp16(mu)) — deduped; mfma kernel's interleaved K-order reuses
// each B chunk for both A sections.
// dot = ah*bh + al*bh ~= (x*L2E).mu (dropped a*bl ~2^-12 rel; 100x margin
// measured: absmax 2.5e-29 vs threshold 2.8e-27).
// xc[m] = -0.5|x|^2*L2E ; mc[n] = (ln w - 0.5|mu|^2)*L2E
// ---------------------------------------------------------------------------
__global__ __launch_bounds__(256) void gmm_prep_f16(
    const float* __restrict__ x, const float* __restrict__ means,
    const float* __restrict__ w, short* __restrict__ Acat,
    short* __restrict__ Bcat, float* __restrict__ xc, float* __restrict__ mc)
{
    const int tid  = threadIdx.x;
    const int rbk  = blockIdx.x;               // 0..1535
    const bool isx = rbk < (MM / 16);
    const int rb   = isx ? rbk : rbk - (MM / 16);
    const int lane = tid & 63;
    const int rp   = (tid >> 6) * 4 + (lane >> 4);   // 0..15 row in block
    const int cg   = lane & 15;                      // col granule 0..15
    const int p    = cg >> 2;                        // chunk 0..3
    const int gk   = cg & 3;
    const int row  = rb * 16 + rp;

    const float* src = (isx ? x : means) + (size_t)row * DD + cg * 8;
    float4 u0 = ((const float4*)src)[0];
    float4 u1 = ((const float4*)src)[1];
    float a[8] = {u0.x, u0.y, u0.z, u0.w, u1.x, u1.y, u1.z, u1.w};

    float ss = 0.f;
    unsigned hi[4], lo[4];
    #pragma unroll
    for (int q = 0; q < 4; ++q) {
        ss = fmaf(a[2 * q], a[2 * q], fmaf(a[2 * q + 1], a[2 * q + 1], ss));
        float a0 = isx ? a[2 * q] * L2E     : a[2 * q];
        float a1 = isx ? a[2 * q + 1] * L2E : a[2 * q + 1];
        unsigned short h0 = f2h(a0), h1 = f2h(a1);
        unsigned short l0 = f2h(a0 - h2f(h0)), l1 = f2h(a1 - h2f(h1));
        hi[q] = (unsigned)h0 | ((unsigned)h1 << 16);
        lo[q] = (unsigned)l0 | ((unsigned)l1 << 16);
    }
    uint4 HI = make_uint4(hi[0], hi[1], hi[2], hi[3]);
    uint4 LO = make_uint4(lo[0], lo[1], lo[2], lo[3]);

    const int slot = rp * 4 + ((gk + (rp >> 1)) & 3);    // bank swizzle
    if (isx) {
        short* base = Acat + (size_t)rb * 4096 + p * 512 + slot * 8;
        *(uint4*)(base)           = HI;                  // chunks 0..3 (hi)
        *(uint4*)(base + 4 * 512) = LO;                  // chunks 4..7 (lo)
    } else {
        short* base = Bcat + (size_t)rb * 2048 + p * 512 + slot * 8;
        *(uint4*)(base) = HI;                            // chunks 0..3 only
    }

    ss += __shfl_xor(ss, 1, 16);
    ss += __shfl_xor(ss, 2, 16);
    ss += __shfl_xor(ss, 4, 16);
    ss += __shfl_xor(ss, 8, 16);
    if (cg == 0) {
        if (isx) xc[row] = -0.5f * ss * L2E;
        else     mc[row] = (logf(w[row]) - 0.5f * ss) * L2E;
    }
}

// ---------------------------------------------------------------------------
// Main MFMA kernel — round-12's interleaved/dedup phase structure, scaled to
// 512-thread blocks: block tile 128x256, 8 waves in a 2x4 grid, wave-tile
// 64x64 (unchanged). Rationale: VGPR use (56+64acc=120 unified) permits
// 4 waves/SIMD -> 16 waves/CU at 2 blocks/CU (vs 12 at 3x256), the one
// occupancy lever not blocked by the (256,4) register-cap instability.
// Per-wave staging drops to <=3 async16/phase; per-block fixed costs
// (prologue drain, xcs, partials) amortize over 2x output elements.
//   bk-iteration = (a_hi_bk . b_bk) then (a_lo_bk . b_bk); B chunk dbuf.
// Hazards identical to the round-12 proven pattern: every prefetch issued
// AFTER a barrier into a buffer whose readers preceded that barrier; every
// read preceded by a barrier draining DMA issued >=1 phase earlier.
// LDS: A dbuf 2x8K + B dbuf 2x16K + xcs 0.5K + red 2K = 50.5 KB -> 2 blk/CU.
// Epilogue: exp2(acc + xc + mc), width-16 shuffle reduce, red[4][128] LDS
// combine across the 4 wn-waves, partials store (no atomics).
// ---------------------------------------------------------------------------
__global__ __launch_bounds__(512, 3) void gmm_mfma(
    const short* __restrict__ Acat, const short* __restrict__ Bcat,
    const float* __restrict__ xc, const float* __restrict__ mc,
    float* __restrict__ partials)
{
    __shared__ __align__(16) short As[2][4096];   // 2 x 8 KB  (A: 128 rows)
    __shared__ __align__(16) short Bs[2][8192];   // 2 x 16 KB (B: 256 rows)
    __shared__ __align__(16) float xcs[128];
    __shared__ float red[4][128];

    const int tid  = threadIdx.x;
    const int w    = tid >> 6, lane = tid & 63;   // w 0..7
    const int wm   = w >> 2,   wn   = w & 3;      // 2 x 4 wave grid
    const int quad = lane >> 4, col = lane & 15;
    const int m0   = blockIdx.x * 128;
    const int nb   = blockIdx.y * 256;

    // staging: wave w owns A row-block w (1 async16/phase) and
    // B row-blocks {2w, 2w+1} (2 async16/phase)
    const short* ga  = Acat + (size_t)(blockIdx.x * 8 + w) * 4096 + lane * 8;
    const short* gb0 = Bcat + (size_t)(blockIdx.y * 16 + w * 2) * 2048 + lane * 8;
    const short* gb1 = gb0 + 2048;
    const int aofs  = w * 512;
    const int bofs0 = w * 1024;
    const int bofs1 = w * 1024 + 512;

    if (tid < 128) xcs[tid] = xc[m0 + tid];   // covered by first K-loop barrier

    // prefetch epilogue constants early (latency hidden by the K-loop)
    float mcv[4];
    #pragma unroll
    for (int j = 0; j < 4; ++j) mcv[j] = mc[nb + wn * 64 + j * 16 + col];

    // prologue: A hi_0 -> As[0], B_0 -> Bs[0]
    async16(&As[0][aofs],  ga);
    async16(&Bs[0][bofs0], gb0);
    async16(&Bs[0][bofs1], gb1);

    f32x4 acc[4][4];
    #pragma unroll
    for (int i = 0; i < 4; ++i)
        #pragma unroll
        for (int j = 0; j < 4; ++j)
            acc[i][j] = (f32x4){0.f, 0.f, 0.f, 0.f};

    // swizzled in-tile read offset (shorts): r'=col, g=quad
    const int rdo = col * 32 + ((quad + (col >> 1)) & 3) * 8;

    #pragma unroll 1
    for (int bk = 0; bk < 4; ++bk) {
        const short* bs = Bs[bk & 1];

        // ---- phase 2*bk : a_hi_bk . b_bk ----
        __syncthreads();   // drains staging issued >=1 phase ago
        async16(&As[1][aofs], ga + (4 + bk) * 512);              // A lo_bk
        if (bk < 3) {
            async16(&Bs[(bk + 1) & 1][bofs0], gb0 + (bk + 1) * 512);  // B_bk+1
            async16(&Bs[(bk + 1) & 1][bofs1], gb1 + (bk + 1) * 512);
        }
        {
            f16x8 af[4];
            #pragma unroll
            for (int i = 0; i < 4; ++i)
                af[i] = *(const f16x8*)(&As[0][(wm * 4 + i) * 512 + rdo]);
            #pragma unroll
            for (int j = 0; j < 4; ++j) {
                f16x8 bfr = *(const f16x8*)(&bs[(wn * 4 + j) * 512 + rdo]);
                #pragma unroll
                for (int i = 0; i < 4; ++i)
                    acc[i][j] = __builtin_amdgcn_mfma_f32_16x16x32_f16(
                        af[i], bfr, acc[i][j], 0, 0, 0);
            }
        }

        // ---- phase 2*bk+1 : a_lo_bk . b_bk ----
        __syncthreads();   // drains A-lo (and early B) staging
        if (bk < 3) {
            async16(&As[0][aofs], ga + (bk + 1) * 512);          // A hi_bk+1
        }
        {
            f16x8 af[4];
            #pragma unroll
            for (int i = 0; i < 4; ++i)
                af[i] = *(const f16x8*)(&As[1][(wm * 4 + i) * 512 + rdo]);
            #pragma unroll
            for (int j = 0; j < 4; ++j) {
                f16x8 bfr = *(const f16x8*)(&bs[(wn * 4 + j) * 512 + rdo]);
                #pragma unroll
                for (int i = 0; i < 4; ++i)
                    acc[i][j] = __builtin_amdgcn_mfma_f32_16x16x32_f16(
                        af[i], bfr, acc[i][j], 0, 0, 0);
            }
        }
    }

    // epilogue: C/D layout col = lane&15, row = quad*4 + reg
    #pragma unroll
    for (int i = 0; i < 4; ++i) {
        float4 xv = *(const float4*)&xcs[wm * 64 + i * 16 + quad * 4];
        float xa[4] = {xv.x, xv.y, xv.z, xv.w};
        #pragma unroll
        for (int r = 0; r < 4; ++r) {
            float s = 0.f;
            #pragma unroll
            for (int j = 0; j < 4; ++j)
                s += __builtin_exp2f(acc[i][j][r] + xa[r] + mcv[j]);
            s += __shfl_xor(s, 1, 16);
            s += __shfl_xor(s, 2, 16);
            s += __shfl_xor(s, 4, 16);
            s += __shfl_xor(s, 8, 16);
            if (col == 0) red[wn][wm * 64 + i * 16 + quad * 4 + r] = s;
        }
    }
    __syncthreads();
    if (tid < 128)
        partials[(size_t)blockIdx.y * MM + m0 + tid] =
            red[0][tid] + red[1][tid] + red[2][tid] + red[3][tid];
}

// ---------------------------------------------------------------------------
// Reduce — 256 blocks (1/CU). Block covers 64 m-values; 4 k-groups of 8
// strips (32 total) summed per thread, combined via LDS.
// ---------------------------------------------------------------------------
__global__ __launch_bounds__(256) void gmm_reduce(
    const float* __restrict__ partials, float* __restrict__ out)
{
    __shared__ float red[4][64];
    const int tid = threadIdx.x;
    const int ml  = tid & 63;
    const int kg  = tid >> 6;
    const int m   = blockIdx.x * 64 + ml;
    float s = 0.f;
    #pragma unroll
    for (int k = 0; k < 8; ++k)
        s += partials[(size_t)(kg * 8 + k) * MM + m];
    red[kg][ml] = s;
    __syncthreads();
    if (tid < 64)
        out[blockIdx.x * 64 + tid] =
            COEF * (red[0][tid] + red[1][tid] + red[2][tid] + red[3][tid]);
}

// ===========================================================================
// Fallback fp32 path (round-1) — only if ws_size is too small.
// ===========================================================================
__global__ __launch_bounds__(256) void gmm_prep(
    const float* __restrict__ x, const float* __restrict__ means,
    const float* __restrict__ w, float* __restrict__ xc, float* __restrict__ mc)
{
    int tid = blockIdx.x * 256 + threadIdx.x;
    if (tid < MM) {
        const float4* row = (const float4*)(x + (size_t)tid * DD);
        float ss = 0.f;
        #pragma unroll
        for (int i = 0; i < DD / 4; ++i) {
            float4 v = row[i];
            ss = fmaf(v.x, v.x, fmaf(v.y, v.y, fmaf(v.z, v.z, fmaf(v.w, v.w, ss))));
        }
        xc[tid] = -0.5f * ss * L2E;
    } else if (tid < MM + NN) {
        int n = tid - MM;
        const float4* row = (const float4*)(means + (size_t)n * DD);
        float ss = 0.f;
        #pragma unroll
        for (int i = 0; i < DD / 4; ++i) {
            float4 v = row[i];
            ss = fmaf(v.x, v.x, fmaf(v.y, v.y, fmaf(v.z, v.z, fmaf(v.w, v.w, ss))));
        }
        mc[n] = (logf(w[n]) - 0.5f * ss) * L2E;
    }
}

__global__ __launch_bounds__(256, 2) void gmm_main(
    const float* __restrict__ x, const float* __restrict__ means,
    const float* __restrict__ xc, const float* __restrict__ mc,
    float* __restrict__ out)
{
    __shared__ __align__(16) float Asm[128 * 128];
    __shared__ __align__(16) float Bsm[2][16 * 128];

    const int t   = threadIdx.x;
    const int tc  = t & 15;
    const int tr  = t >> 4;
    const int r0  = blockIdx.x * 128;
    const int nq0 = blockIdx.y * 2048;

    {
        float4 tmp[16];
        #pragma unroll
        for (int ii = 0; ii < 16; ++ii) {
            int idx = t + ii * 256;
            int r   = idx >> 5;
            int k0  = (idx & 31) << 2;
            tmp[ii] = *(const float4*)(x + (size_t)(r0 + r) * DD + k0);
        }
        #pragma unroll
        for (int ii = 0; ii < 16; ++ii) {
            int idx = t + ii * 256;
            int r   = idx >> 5;
            int k0  = (idx & 31) << 2;
            int rb  = r >> 3, rl = r & 7;
            float v[4] = {tmp[ii].x, tmp[ii].y, tmp[ii].z, tmp[ii].w};
            #pragma unroll
            for (int j = 0; j < 4; ++j) {
                int k = k0 + j;
                Asm[k * 128 + (((rb ^ (k & 15)) << 3) | rl)] = v[j];
            }
        }
    }

    float xcv[8];
    {
        float4 a = *(const float4*)(xc + r0 + tr * 8);
        float4 b = *(const float4*)(xc + r0 + tr * 8 + 4);
        xcv[0] = a.x; xcv[1] = a.y; xcv[2] = a.z; xcv[3] = a.w;
        xcv[4] = b.x; xcv[5] = b.y; xcv[6] = b.z; xcv[7] = b.w;
    }

    float rowAcc[8];
    #pragma unroll
    for (int i = 0; i < 8; ++i) rowAcc[i] = 0.f;

    for (int ntile = 0; ntile < 16; ++ntile) {
        const int nbase = nq0 + ntile * 128;

        float acc[8][8];
        #pragma unroll
        for (int i = 0; i < 8; ++i)
            #pragma unroll
            for (int j = 0; j < 8; ++j) acc[i][j] = 0.f;

        float4 ld[2];
        #pragma unroll
        for (int ii = 0; ii < 2; ++ii) {
            int flat = t + ii * 256;
            int nl   = flat >> 2;
            int kl   = (flat & 3) << 2;
            ld[ii] = *(const float4*)(means + (size_t)(nbase + nl) * DD + kl);
        }

        for (int ks = 0; ks < 8; ++ks) {
            const int buf = ks & 1;
            #pragma unroll
            for (int ii = 0; ii < 2; ++ii) {
                int flat = t + ii * 256;
                int nl   = flat >> 2;
                int k0   = (flat & 3) << 2;
                int nbk  = nl >> 3, nll = nl & 7;
                float v[4] = {ld[ii].x, ld[ii].y, ld[ii].z, ld[ii].w};
                #pragma unroll
                for (int j = 0; j < 4; ++j) {
                    int kl = k0 + j;
                    Bsm[buf][kl * 128 + (((nbk ^ kl) << 3) | nll)] = v[j];
                }
            }
            if (ks < 7) {
                #pragma unroll
                for (int ii = 0; ii < 2; ++ii) {
                    int flat = t + ii * 256;
                    int nl   = flat >> 2;
                    int kl   = (flat & 3) << 2;
                    ld[ii] = *(const float4*)(means + (size_t)(nbase + nl) * DD
                                              + (ks + 1) * 16 + kl);
                }
            }
            __syncthreads();

            #pragma unroll
            for (int kk = 0; kk < 16; ++kk) {
                const int k = ks * 16 + kk;
                const float* apx = &Asm[k * 128 + ((tr ^ kk) << 3)];
                float4 a0 = *(const float4*)apx;
                float4 a1 = *(const float4*)(apx + 4);
                const float* bpx = &Bsm[buf][kk * 128 + ((tc ^ kk) << 3)];
                float4 b0 = *(const float4*)bpx;
                float4 b1 = *(const float4*)(bpx + 4);
                float av[8] = {a0.x, a0.y, a0.z, a0.w, a1.x, a1.y, a1.z, a1.w};
                float bv[8] = {b0.x, b0.y, b0.z, b0.w, b1.x, b1.y, b1.z, b1.w};
                #pragma unroll
                for (int i = 0; i < 8; ++i)
                    #pragma unroll
                    for (int j = 0; j < 8; ++j)
                        acc[i][j] = fmaf(av[i], bv[j], acc[i][j]);
            }
        }

        float mcv[8];
        {
            float4 a = *(const float4*)(mc + nbase + tc * 8);
            float4 b = *(const float4*)(mc + nbase + tc * 8 + 4);
            mcv[0] = a.x; mcv[1] = a.y; mcv[2] = a.z; mcv[3] = a.w;
            mcv[4] = b.x; mcv[5] = b.y; mcv[6] = b.z; mcv[7] = b.w;
        }
        #pragma unroll
        for (int i = 0; i < 8; ++i) {
            float s = 0.f;
            #pragma unroll
            for (int j = 0; j < 8; ++j) {
                float arg = fmaf(acc[i][j], L2E, xcv[i] + mcv[j]);
                s += __builtin_exp2f(arg);
            }
            rowAcc[i] += s;
        }
    }

    #pragma unroll
    for (int i = 0; i < 8; ++i) {
        float v = rowAcc[i];
        v += __shfl_xor(v, 1, 16);
        v += __shfl_xor(v, 2, 16);
        v += __shfl_xor(v, 4, 16);
        v += __shfl_xor(v, 8, 16);
        if (tc == 0) atomicAdd(out + r0 + tr * 8 + i, COEF * v);
    }
}

extern "C" void kernel_launch(void* const* d_in, const int* in_sizes, int n_in,
                              void* d_out, int out_size, void* d_ws, size_t ws_size,
                              hipStream_t stream) {
    const float* x     = (const float*)d_in[0];
    const float* means = (const float*)d_in[1];
    const float* w     = (const float*)d_in[2];
    float* out = (float*)d_out;

    const size_t needA = (size_t)MM * 256 * sizeof(short);   // 8.4 MB
    const size_t needB = (size_t)NN * 128 * sizeof(short);   // 2.1 MB (dedup)
    const size_t need  = needA + needB + (size_t)(MM + NN) * 4
                       + (size_t)32 * MM * 4;                // + partials 2 MB

    if (ws_size >= need) {
        short* Acat     = (short*)d_ws;
        short* Bcat     = Acat + (size_t)MM * 256;
        float* xc       = (float*)(Bcat + (size_t)NN * 128);
        float* mc       = xc + MM;
        float* partials = mc + NN;
        gmm_prep_f16<<<(MM + NN) / 16, 256, 0, stream>>>(x, means, w, Acat, Bcat, xc, mc);
        gmm_mfma<<<dim3(MM / 128, NN / 256), 512, 0, stream>>>(Acat, Bcat, xc, mc, partials);
        gmm_reduce<<<MM / 64, 256, 0, stream>>>(partials, out);
    } else {
        float* xc = (float*)d_ws;
        float* mc = xc + MM;
        hipMemsetAsync(out, 0, MM * sizeof(float), stream);
        gmm_prep<<<(MM + NN + 255) / 256, 256, 0, stream>>>(x, means, w, xc, mc);
        gmm_main<<<dim3(MM / 128, 4), 256, 0, stream>>>(x, means, xc, mc, out);
    }
}

// Round 14
// 152.630 us; speedup vs baseline: 1.0481x; 1.0481x over previous
//
#include <hip/hip_runtime.h>
#include <math.h>

#define MM 16384
#define NN 8192
#define DD 128

#define L2E  1.4426950408889634f
#define COEF 0.15915494309189535f   // 1/(2*pi)

// ---------------------------------------------------------------------------
// fp16 helpers (RNE via v_cvt_f16_f32)
// ---------------------------------------------------------------------------
__device__ __forceinline__ unsigned short f2h(float f) {
    _Float16 h = (_Float16)f;
    unsigned short u;
    __builtin_memcpy(&u, &h, 2);
    return u;
}
__device__ __forceinline__ float h2f(unsigned short u) {
    _Float16 h;
    __builtin_memcpy(&h, &u, 2);
    return (float)h;
}

__device__ __forceinline__ void async16(short* lds, const short* g) {
    __builtin_amdgcn_global_load_lds(
        (const __attribute__((address_space(1))) unsigned int*)g,
        (__attribute__((address_space(3))) unsigned int*)lds,
        16, 0, 0);
}

typedef __attribute__((ext_vector_type(8))) _Float16 f16x8;
typedef __attribute__((ext_vector_type(4))) float f32x4;

// ---------------------------------------------------------------------------
// Pre-pass v4 (unchanged) — one 16-row block per 256-thread block.
// Layout: Cat = [rowblock rb][chunk][64 granules of 16B], granule (rp,gk) at
// slot rp*4+((gk+(rp>>1))&3) (bank swizzle -> post-DMA LDS frag reads
// conflict-free). A: 8 chunks (0-3 = fp16(x*L2E) hi, 4-7 = fp16 residual).
// B: 4 chunks (fp16(mu)) — deduped; mfma kernel's interleaved K-order reuses
// each B chunk for both A sections.
// dot = ah*bh + al*bh ~= (x*L2E).mu (dropped a*bl ~2^-12 rel; 100x margin
// measured: absmax 2.5e-29 vs threshold 2.8e-27).
// xc[m] = -0.5|x|^2*L2E ; mc[n] = (ln w - 0.5|mu|^2)*L2E
// ---------------------------------------------------------------------------
__global__ __launch_bounds__(256) void gmm_prep_f16(
    const float* __restrict__ x, const float* __restrict__ means,
    const float* __restrict__ w, short* __restrict__ Acat,
    short* __restrict__ Bcat, float* __restrict__ xc, float* __restrict__ mc)
{
    const int tid  = threadIdx.x;
    const int rbk  = blockIdx.x;               // 0..1535
    const bool isx = rbk < (MM / 16);
    const int rb   = isx ? rbk : rbk - (MM / 16);
    const int lane = tid & 63;
    const int rp   = (tid >> 6) * 4 + (lane >> 4);   // 0..15 row in block
    const int cg   = lane & 15;                      // col granule 0..15
    const int p    = cg >> 2;                        // chunk 0..3
    const int gk   = cg & 3;
    const int row  = rb * 16 + rp;

    const float* src = (isx ? x : means) + (size_t)row * DD + cg * 8;
    float4 u0 = ((const float4*)src)[0];
    float4 u1 = ((const float4*)src)[1];
    float a[8] = {u0.x, u0.y, u0.z, u0.w, u1.x, u1.y, u1.z, u1.w};

    float ss = 0.f;
    unsigned hi[4], lo[4];
    #pragma unroll
    for (int q = 0; q < 4; ++q) {
        ss = fmaf(a[2 * q], a[2 * q], fmaf(a[2 * q + 1], a[2 * q + 1], ss));
        float a0 = isx ? a[2 * q] * L2E     : a[2 * q];
        float a1 = isx ? a[2 * q + 1] * L2E : a[2 * q + 1];
        unsigned short h0 = f2h(a0), h1 = f2h(a1);
        unsigned short l0 = f2h(a0 - h2f(h0)), l1 = f2h(a1 - h2f(h1));
        hi[q] = (unsigned)h0 | ((unsigned)h1 << 16);
        lo[q] = (unsigned)l0 | ((unsigned)l1 << 16);
    }
    uint4 HI = make_uint4(hi[0], hi[1], hi[2], hi[3]);
    uint4 LO = make_uint4(lo[0], lo[1], lo[2], lo[3]);

    const int slot = rp * 4 + ((gk + (rp >> 1)) & 3);    // bank swizzle
    if (isx) {
        short* base = Acat + (size_t)rb * 4096 + p * 512 + slot * 8;
        *(uint4*)(base)           = HI;                  // chunks 0..3 (hi)
        *(uint4*)(base + 4 * 512) = LO;                  // chunks 4..7 (lo)
    } else {
        short* base = Bcat + (size_t)rb * 2048 + p * 512 + slot * 8;
        *(uint4*)(base) = HI;                            // chunks 0..3 only
    }

    ss += __shfl_xor(ss, 1, 16);
    ss += __shfl_xor(ss, 2, 16);
    ss += __shfl_xor(ss, 4, 16);
    ss += __shfl_xor(ss, 8, 16);
    if (cg == 0) {
        if (isx) xc[row] = -0.5f * ss * L2E;
        else     mc[row] = (logf(w[row]) - 0.5f * ss) * L2E;
    }
}

// ---------------------------------------------------------------------------
// Main MFMA kernel — round-13 K-loop (512 threads, 128x256 tile, 8 waves 2x4,
// interleaved dedup phases, 2-buffer A + 2-buffer B staging, prefetch after
// barrier) with a NEW epilogue: the 64-shuffle-per-thread reduce (512
// ds_swizzle wave-ops/block on the LDS pipe) is replaced by an LDS-matrix
// reduction that REUSES the dead K-loop staging memory:
//   S[m_local][stride 68] (aliases As/Bs; stride 68 -> bank 16(quad&1)+4r+col
//   = exactly 2-way per b32 write, free per m136) ; 16 ds_write_b32/thread,
//   then 512 threads re-read row-contiguous (4x ds_read_b128, canonical
//   pattern) and combine via red[4][128]. ~1100 cyc/block vs ~3000.
// LDS: smem 48 KB (As 2x8K | Bs 2x16K, aliased by S 34.8 KB) + xcs + red.
// ---------------------------------------------------------------------------
__global__ __launch_bounds__(512, 3) void gmm_mfma(
    const short* __restrict__ Acat, const short* __restrict__ Bcat,
    const float* __restrict__ xc, const float* __restrict__ mc,
    float* __restrict__ partials)
{
    __shared__ __align__(16) short smem[24576];   // 48 KB: A dbuf | B dbuf | S
    __shared__ __align__(16) float xcs[128];
    __shared__ float red[4][128];

#define AS(b) (smem + (b) * 4096)
#define BS(b) (smem + 8192 + (b) * 8192)

    const int tid  = threadIdx.x;
    const int w    = tid >> 6, lane = tid & 63;   // w 0..7
    const int wm   = w >> 2,   wn   = w & 3;      // 2 x 4 wave grid
    const int quad = lane >> 4, col = lane & 15;
    const int m0   = blockIdx.x * 128;
    const int nb   = blockIdx.y * 256;

    // staging: wave w owns A row-block w (1 async16/phase) and
    // B row-blocks {2w, 2w+1} (2 async16/phase)
    const short* ga  = Acat + (size_t)(blockIdx.x * 8 + w) * 4096 + lane * 8;
    const short* gb0 = Bcat + (size_t)(blockIdx.y * 16 + w * 2) * 2048 + lane * 8;
    const short* gb1 = gb0 + 2048;
    const int aofs  = w * 512;
    const int bofs0 = w * 1024;
    const int bofs1 = w * 1024 + 512;

    if (tid < 128) xcs[tid] = xc[m0 + tid];   // covered by first K-loop barrier

    // prefetch epilogue constants early (latency hidden by the K-loop)
    float mcv[4];
    #pragma unroll
    for (int j = 0; j < 4; ++j) mcv[j] = mc[nb + wn * 64 + j * 16 + col];

    // prologue: A hi_0 -> As[0], B_0 -> Bs[0]
    async16(AS(0) + aofs,  ga);
    async16(BS(0) + bofs0, gb0);
    async16(BS(0) + bofs1, gb1);

    f32x4 acc[4][4];
    #pragma unroll
    for (int i = 0; i < 4; ++i)
        #pragma unroll
        for (int j = 0; j < 4; ++j)
            acc[i][j] = (f32x4){0.f, 0.f, 0.f, 0.f};

    // swizzled in-tile read offset (shorts): r'=col, g=quad
    const int rdo = col * 32 + ((quad + (col >> 1)) & 3) * 8;

    #pragma unroll 1
    for (int bk = 0; bk < 4; ++bk) {
        const short* bs = BS(bk & 1);

        // ---- phase 2*bk : a_hi_bk . b_bk ----
        __syncthreads();   // drains staging issued >=1 phase ago
        async16(AS(1) + aofs, ga + (4 + bk) * 512);              // A lo_bk
        if (bk < 3) {
            async16(BS((bk + 1) & 1) + bofs0, gb0 + (bk + 1) * 512);  // B_bk+1
            async16(BS((bk + 1) & 1) + bofs1, gb1 + (bk + 1) * 512);
        }
        {
            f16x8 af[4];
            #pragma unroll
            for (int i = 0; i < 4; ++i)
                af[i] = *(const f16x8*)(AS(0) + (wm * 4 + i) * 512 + rdo);
            #pragma unroll
            for (int j = 0; j < 4; ++j) {
                f16x8 bfr = *(const f16x8*)(&bs[(wn * 4 + j) * 512 + rdo]);
                #pragma unroll
                for (int i = 0; i < 4; ++i)
                    acc[i][j] = __builtin_amdgcn_mfma_f32_16x16x32_f16(
                        af[i], bfr, acc[i][j], 0, 0, 0);
            }
        }

        // ---- phase 2*bk+1 : a_lo_bk . b_bk ----
        __syncthreads();   // drains A-lo (and early B) staging
        if (bk < 3) {
            async16(AS(0) + aofs, ga + (bk + 1) * 512);          // A hi_bk+1
        }
        {
            f16x8 af[4];
            #pragma unroll
            for (int i = 0; i < 4; ++i)
                af[i] = *(const f16x8*)(AS(1) + (wm * 4 + i) * 512 + rdo);
            #pragma unroll
            for (int j = 0; j < 4; ++j) {
                f16x8 bfr = *(const f16x8*)(&bs[(wn * 4 + j) * 512 + rdo]);
                #pragma unroll
                for (int i = 0; i < 4; ++i)
                    acc[i][j] = __builtin_amdgcn_mfma_f32_16x16x32_f16(
                        af[i], bfr, acc[i][j], 0, 0, 0);
            }
        }
    }

    // ---- epilogue v2 ----
    // 1) per-thread j-summed exp2 partials (C/D layout: col=lane&15,
    //    row = quad*4 + reg)
    float sv[4][4];
    #pragma unroll
    for (int i = 0; i < 4; ++i) {
        float4 xv = *(const float4*)&xcs[wm * 64 + i * 16 + quad * 4];
        float xa[4] = {xv.x, xv.y, xv.z, xv.w};
        #pragma unroll
        for (int r = 0; r < 4; ++r) {
            float s = 0.f;
            #pragma unroll
            for (int j = 0; j < 4; ++j)
                s += __builtin_exp2f(acc[i][j][r] + xa[r] + mcv[j]);
            sv[i][r] = s;
        }
    }
    // 2) scatter to S[m_local][p] (aliases dead K-loop staging; stride 68
    //    floats -> 2-way bank aliasing on writes = free)
    __syncthreads();   // all K-loop LDS reads complete before overwrite
    {
        float* S = (float*)smem;
        const int p = wn * 16 + col;
        #pragma unroll
        for (int i = 0; i < 4; ++i) {
            const int mb = wm * 64 + i * 16 + quad * 4;
            #pragma unroll
            for (int r = 0; r < 4; ++r)
                S[(mb + r) * 68 + p] = sv[i][r];
        }
    }
    __syncthreads();
    // 3) 512 threads: row-contiguous b128 re-read, 16-way sum -> red[pg][m]
    {
        const float* S = (const float*)smem;
        const int m  = tid & 127;
        const int pg = tid >> 7;
        const float4* v = (const float4*)(S + m * 68 + pg * 16);
        float4 a0 = v[0], a1 = v[1], a2 = v[2], a3 = v[3];
        red[pg][m] = (a0.x + a0.y + a0.z + a0.w) + (a1.x + a1.y + a1.z + a1.w)
                   + (a2.x + a2.y + a2.z + a2.w) + (a3.x + a3.y + a3.z + a3.w);
    }
    __syncthreads();
    if (tid < 128)
        partials[(size_t)blockIdx.y * MM + m0 + tid] =
            red[0][tid] + red[1][tid] + red[2][tid] + red[3][tid];
#undef AS
#undef BS
}

// ---------------------------------------------------------------------------
// Reduce — 256 blocks (1/CU). Block covers 64 m-values; 4 k-groups of 8
// strips (32 total) summed per thread, combined via LDS.
// ---------------------------------------------------------------------------
__global__ __launch_bounds__(256) void gmm_reduce(
    const float* __restrict__ partials, float* __restrict__ out)
{
    __shared__ float red[4][64];
    const int tid = threadIdx.x;
    const int ml  = tid & 63;
    const int kg  = tid >> 6;
    const int m   = blockIdx.x * 64 + ml;
    float s = 0.f;
    #pragma unroll
    for (int k = 0; k < 8; ++k)
        s += partials[(size_t)(kg * 8 + k) * MM + m];
    red[kg][ml] = s;
    __syncthreads();
    if (tid < 64)
        out[blockIdx.x * 64 + tid] =
            COEF * (red[0][tid] + red[1][tid] + red[2][tid] + red[3][tid]);
}

// ===========================================================================
// Fallback fp32 path (round-1) — only if ws_size is too small.
// ===========================================================================
__global__ __launch_bounds__(256) void gmm_prep(
    const float* __restrict__ x, const float* __restrict__ means,
    const float* __restrict__ w, float* __restrict__ xc, float* __restrict__ mc)
{
    int tid = blockIdx.x * 256 + threadIdx.x;
    if (tid < MM) {
        const float4* row = (const float4*)(x + (size_t)tid * DD);
        float ss = 0.f;
        #pragma unroll
        for (int i = 0; i < DD / 4; ++i) {
            float4 v = row[i];
            ss = fmaf(v.x, v.x, fmaf(v.y, v.y, fmaf(v.z, v.z, fmaf(v.w, v.w, ss))));
        }
        xc[tid] = -0.5f * ss * L2E;
    } else if (tid < MM + NN) {
        int n = tid - MM;
        const float4* row = (const float4*)(means + (size_t)n * DD);
        float ss = 0.f;
        #pragma unroll
        for (int i = 0; i < DD / 4; ++i) {
            float4 v = row[i];
            ss = fmaf(v.x, v.x, fmaf(v.y, v.y, fmaf(v.z, v.z, fmaf(v.w, v.w, ss))));
        }
        mc[n] = (logf(w[n]) - 0.5f * ss) * L2E;
    }
}

__global__ __launch_bounds__(256, 2) void gmm_main(
    const float* __restrict__ x, const float* __restrict__ means,
    const float* __restrict__ xc, const float* __restrict__ mc,
    float* __restrict__ out)
{
    __shared__ __align__(16) float Asm[128 * 128];
    __shared__ __align__(16) float Bsm[2][16 * 128];

    const int t   = threadIdx.x;
    const int tc  = t & 15;
    const int tr  = t >> 4;
    const int r0  = blockIdx.x * 128;
    const int nq0 = blockIdx.y * 2048;

    {
        float4 tmp[16];
        #pragma unroll
        for (int ii = 0; ii < 16; ++ii) {
            int idx = t + ii * 256;
            int r   = idx >> 5;
            int k0  = (idx & 31) << 2;
            tmp[ii] = *(const float4*)(x + (size_t)(r0 + r) * DD + k0);
        }
        #pragma unroll
        for (int ii = 0; ii < 16; ++ii) {
            int idx = t + ii * 256;
            int r   = idx >> 5;
            int k0  = (idx & 31) << 2;
            int rb  = r >> 3, rl = r & 7;
            float v[4] = {tmp[ii].x, tmp[ii].y, tmp[ii].z, tmp[ii].w};
            #pragma unroll
            for (int j = 0; j < 4; ++j) {
                int k = k0 + j;
                Asm[k * 128 + (((rb ^ (k & 15)) << 3) | rl)] = v[j];
            }
        }
    }

    float xcv[8];
    {
        float4 a = *(const float4*)(xc + r0 + tr * 8);
        float4 b = *(const float4*)(xc + r0 + tr * 8 + 4);
        xcv[0] = a.x; xcv[1] = a.y; xcv[2] = a.z; xcv[3] = a.w;
        xcv[4] = b.x; xcv[5] = b.y; xcv[6] = b.z; xcv[7] = b.w;
    }

    float rowAcc[8];
    #pragma unroll
    for (int i = 0; i < 8; ++i) rowAcc[i] = 0.f;

    for (int ntile = 0; ntile < 16; ++ntile) {
        const int nbase = nq0 + ntile * 128;

        float acc[8][8];
        #pragma unroll
        for (int i = 0; i < 8; ++i)
            #pragma unroll
            for (int j = 0; j < 8; ++j) acc[i][j] = 0.f;

        float4 ld[2];
        #pragma unroll
        for (int ii = 0; ii < 2; ++ii) {
            int flat = t + ii * 256;
            int nl   = flat >> 2;
            int kl   = (flat & 3) << 2;
            ld[ii] = *(const float4*)(means + (size_t)(nbase + nl) * DD + kl);
        }

        for (int ks = 0; ks < 8; ++ks) {
            const int buf = ks & 1;
            #pragma unroll
            for (int ii = 0; ii < 2; ++ii) {
                int flat = t + ii * 256;
                int nl   = flat >> 2;
                int k0   = (flat & 3) << 2;
                int nbk  = nl >> 3, nll = nl & 7;
                float v[4] = {ld[ii].x, ld[ii].y, ld[ii].z, ld[ii].w};
                #pragma unroll
                for (int j = 0; j < 4; ++j) {
                    int kl = k0 + j;
                    Bsm[buf][kl * 128 + (((nbk ^ kl) << 3) | nll)] = v[j];
                }
            }
            if (ks < 7) {
                #pragma unroll
                for (int ii = 0; ii < 2; ++ii) {
                    int flat = t + ii * 256;
                    int nl   = flat >> 2;
                    int kl   = (flat & 3) << 2;
                    ld[ii] = *(const float4*)(means + (size_t)(nbase + nl) * DD
                                              + (ks + 1) * 16 + kl);
                }
            }
            __syncthreads();

            #pragma unroll
            for (int kk = 0; kk < 16; ++kk) {
                const int k = ks * 16 + kk;
                const float* apx = &Asm[k * 128 + ((tr ^ kk) << 3)];
                float4 a0 = *(const float4*)apx;
                float4 a1 = *(const float4*)(apx + 4);
                const float* bpx = &Bsm[buf][kk * 128 + ((tc ^ kk) << 3)];
                float4 b0 = *(const float4*)bpx;
                float4 b1 = *(const float4*)(bpx + 4);
                float av[8] = {a0.x, a0.y, a0.z, a0.w, a1.x, a1.y, a1.z, a1.w};
                float bv[8] = {b0.x, b0.y, b0.z, b0.w, b1.x, b1.y, b1.z, b1.w};
                #pragma unroll
                for (int i = 0; i < 8; ++i)
                    #pragma unroll
                    for (int j = 0; j < 8; ++j)
                        acc[i][j] = fmaf(av[i], bv[j], acc[i][j]);
            }
        }

        float mcv[8];
        {
            float4 a = *(const float4*)(mc + nbase + tc * 8);
            float4 b = *(const float4*)(mc + nbase + tc * 8 + 4);
            mcv[0] = a.x; mcv[1] = a.y; mcv[2] = a.z; mcv[3] = a.w;
            mcv[4] = b.x; mcv[5] = b.y; mcv[6] = b.z; mcv[7] = b.w;
        }
        #pragma unroll
        for (int i = 0; i < 8; ++i) {
            float s = 0.f;
            #pragma unroll
            for (int j = 0; j < 8; ++j) {
                float arg = fmaf(acc[i][j], L2E, xcv[i] + mcv[j]);
                s += __builtin_exp2f(arg);
            }
            rowAcc[i] += s;
        }
    }

    #pragma unroll
    for (int i = 0; i < 8; ++i) {
        float v = rowAcc[i];
        v += __shfl_xor(v, 1, 16);
        v += __shfl_xor(v, 2, 16);
        v += __shfl_xor(v, 4, 16);
        v += __shfl_xor(v, 8, 16);
        if (tc == 0) atomicAdd(out + r0 + tr * 8 + i, COEF * v);
    }
}

extern "C" void kernel_launch(void* const* d_in, const int* in_sizes, int n_in,
                              void* d_out, int out_size, void* d_ws, size_t ws_size,
                              hipStream_t stream) {
    const float* x     = (const float*)d_in[0];
    const float* means = (const float*)d_in[1];
    const float* w     = (const float*)d_in[2];
    float* out = (float*)d_out;

    const size_t needA = (size_t)MM * 256 * sizeof(short);   // 8.4 MB
    const size_t needB = (size_t)NN * 128 * sizeof(short);   // 2.1 MB (dedup)
    const size_t need  = needA + needB + (size_t)(MM + NN) * 4
                       + (size_t)32 * MM * 4;                // + partials 2 MB

    if (ws_size >= need) {
        short* Acat     = (short*)d_ws;
        short* Bcat     = Acat + (size_t)MM * 256;
        float* xc       = (float*)(Bcat + (size_t)NN * 128);
        float* mc       = xc + MM;
        float* partials = mc + NN;
        gmm_prep_f16<<<(MM + NN) / 16, 256, 0, stream>>>(x, means, w, Acat, Bcat, xc, mc);
        gmm_mfma<<<dim3(MM / 128, NN / 256), 512, 0, stream>>>(Acat, Bcat, xc, mc, partials);
        gmm_reduce<<<MM / 64, 256, 0, stream>>>(partials, out);
    } else {
        float* xc = (float*)d_ws;
        float* mc = xc + MM;
        hipMemsetAsync(out, 0, MM * sizeof(float), stream);
        gmm_prep<<<(MM + NN + 255) / 256, 256, 0, stream>>>(x, means, w, xc, mc);
        gmm_main<<<dim3(MM / 128, 4), 256, 0, stream>>>(x, means, xc, mc, out);
    }
}